// Round 1
// baseline (718.044 us; speedup 1.0000x reference)
//
#include <hip/hip_runtime.h>

#define S_SEQ 2048
#define R_RES 384
#define CIN   64
#define HC    64
#define NH    8
#define CHD   8

// ---------------------------------------------------------------------------
// Helpers
// ---------------------------------------------------------------------------
__device__ __forceinline__ void load_ln_row(const float* __restrict__ row,
                                            const float* __restrict__ lnw,
                                            const float* __restrict__ lnb,
                                            float* x) {
  #pragma unroll
  for (int c4 = 0; c4 < CIN / 4; ++c4) {
    float4 v = reinterpret_cast<const float4*>(row)[c4];
    x[c4 * 4 + 0] = v.x; x[c4 * 4 + 1] = v.y;
    x[c4 * 4 + 2] = v.z; x[c4 * 4 + 3] = v.w;
  }
  float mean = 0.f;
  #pragma unroll
  for (int c = 0; c < CIN; ++c) mean += x[c];
  mean *= (1.0f / CIN);
  float var = 0.f;
  #pragma unroll
  for (int c = 0; c < CIN; ++c) { float d = x[c] - mean; var += d * d; }
  var *= (1.0f / CIN);
  const float rstd = rsqrtf(var + 1e-5f);
  #pragma unroll
  for (int c = 0; c < CIN; ++c) x[c] = (x[c] - mean) * rstd * lnw[c] + lnb[c];
}

// ---------------------------------------------------------------------------
// Kernel 1: LayerNorm + (optional) K/V projection store + masked pooled sums
// grid: (R_RES, S_SEQ/256), block: 256. Thread t handles s = chunk*256+t, row r.
// ---------------------------------------------------------------------------
template <bool STORE_KV>
__global__ __launch_bounds__(256) void k1_ln_kv_pool(
    const float* __restrict__ m, const float* __restrict__ mask,
    const float* __restrict__ ln_w, const float* __restrict__ ln_b,
    const float* __restrict__ wk, const float* __restrict__ wv,
    float* __restrict__ Kd, float* __restrict__ Vd,
    float* __restrict__ qpool_part) {
  const int r = blockIdx.x;
  const int chunk = blockIdx.y;
  const int tid = threadIdx.x;
  const int lane = tid & 63;
  const int wave = tid >> 6;
  const int s = chunk * 256 + tid;

  __shared__ float s_wk[CIN * CHD];
  __shared__ float s_wv[CIN * CHD];
  __shared__ float s_lnw[CIN], s_lnb[CIN];
  __shared__ float red[4][CIN];

  if (STORE_KV) {
    for (int i = tid; i < CIN * CHD; i += 256) { s_wk[i] = wk[i]; s_wv[i] = wv[i]; }
  }
  if (tid < CIN) { s_lnw[tid] = ln_w[tid]; s_lnb[tid] = ln_b[tid]; }
  __syncthreads();

  float x[CIN];
  load_ln_row(m + ((size_t)s * R_RES + r) * CIN, s_lnw, s_lnb, x);

  if (STORE_KV) {
    float kk[CHD], vv[CHD];
    #pragma unroll
    for (int j = 0; j < CHD; ++j) { kk[j] = 0.f; vv[j] = 0.f; }
    #pragma unroll
    for (int c = 0; c < CIN; ++c) {
      const float xc = x[c];
      #pragma unroll
      for (int j = 0; j < CHD; ++j) {
        kk[j] += xc * s_wk[c * CHD + j];
        vv[j] += xc * s_wv[c * CHD + j];
      }
    }
    float* kp = Kd + ((size_t)r * S_SEQ + s) * CHD;
    float* vp = Vd + ((size_t)r * S_SEQ + s) * CHD;
    *reinterpret_cast<float4*>(kp + 0) = make_float4(kk[0], kk[1], kk[2], kk[3]);
    *reinterpret_cast<float4*>(kp + 4) = make_float4(kk[4], kk[5], kk[6], kk[7]);
    *reinterpret_cast<float4*>(vp + 0) = make_float4(vv[0], vv[1], vv[2], vv[3]);
    *reinterpret_cast<float4*>(vp + 4) = make_float4(vv[4], vv[5], vv[6], vv[7]);
  }

  // masked pooled sum over the 256 s-values of this block
  const float mk = mask[(size_t)s * R_RES + r];
  float keep = 0.f;
  #pragma unroll
  for (int c = 0; c < CIN; ++c) {
    float val = x[c] * mk;
    #pragma unroll
    for (int off = 32; off >= 1; off >>= 1) val += __shfl_xor(val, off, 64);
    if (lane == c) keep = val;  // lane c keeps channel c's wave total
  }
  red[wave][lane] = keep;
  __syncthreads();
  if (tid < CIN) {
    float tot = red[0][tid] + red[1][tid] + red[2][tid] + red[3][tid];
    qpool_part[((size_t)chunk * R_RES + r) * CIN + tid] = tot;
  }
}

// ---------------------------------------------------------------------------
// Kernel 2: per-residue global attention. grid: R_RES blocks of 256.
// ---------------------------------------------------------------------------
template <bool USE_KV>
__global__ __launch_bounds__(256) void k2_attn(
    const float* __restrict__ m, const float* __restrict__ mask,
    const float* __restrict__ ln_w, const float* __restrict__ ln_b,
    const float* __restrict__ wq, const float* __restrict__ wk,
    const float* __restrict__ wv, const float* __restrict__ qpool_part,
    const float* __restrict__ Kd, const float* __restrict__ Vd,
    float* __restrict__ od) {
  const int r = blockIdx.x;
  const int tid = threadIdx.x;
  const int lane = tid & 63;
  const int wave = tid >> 6;

  __shared__ float s_q[HC];
  __shared__ float s_qp[CIN];
  __shared__ float s_wk[CIN * CHD], s_wv[CIN * CHD];
  __shared__ float s_lnw[CIN], s_lnb[CIN];
  __shared__ float redw[4][CIN];
  __shared__ float dred[4][NH];
  __shared__ float mred[4][NH];

  if (!USE_KV) {
    for (int i = tid; i < CIN * CHD; i += 256) { s_wk[i] = wk[i]; s_wv[i] = wv[i]; }
    if (tid < CIN) { s_lnw[tid] = ln_w[tid]; s_lnb[tid] = ln_b[tid]; }
  }

  // mask sum over s for this residue
  float msum = 0.f;
  for (int s = tid; s < S_SEQ; s += 256) msum += mask[(size_t)s * R_RES + r];
  #pragma unroll
  for (int off = 32; off >= 1; off >>= 1) msum += __shfl_xor(msum, off, 64);
  if (lane == 0) redw[wave][0] = msum;
  __syncthreads();
  const float msum_tot = redw[0][0] + redw[1][0] + redw[2][0] + redw[3][0];
  __syncthreads();

  // pooled q -> q vector
  if (tid < CIN) {
    float qp = 0.f;
    #pragma unroll
    for (int ch = 0; ch < S_SEQ / 256; ++ch)
      qp += qpool_part[((size_t)ch * R_RES + r) * CIN + tid];
    s_qp[tid] = qp / (msum_tot + 1e-10f);
  }
  __syncthreads();
  if (tid < HC) {
    float qj = 0.f;
    for (int c = 0; c < CIN; ++c) qj += s_qp[c] * wq[c * HC + tid];
    s_q[tid] = qj * 0.35355339059327373f;  // 1/sqrt(8)
  }
  __syncthreads();

  // ---- pass A: per-head max of logits ----
  float hmax[NH];
  #pragma unroll
  for (int h = 0; h < NH; ++h) hmax[h] = -1e30f;

  for (int s = tid; s < S_SEQ; s += 256) {
    float kk[CHD];
    if (USE_KV) {
      const float4* kp = reinterpret_cast<const float4*>(Kd + ((size_t)r * S_SEQ + s) * CHD);
      float4 a = kp[0], b = kp[1];
      kk[0] = a.x; kk[1] = a.y; kk[2] = a.z; kk[3] = a.w;
      kk[4] = b.x; kk[5] = b.y; kk[6] = b.z; kk[7] = b.w;
    } else {
      float x[CIN];
      load_ln_row(m + ((size_t)s * R_RES + r) * CIN, s_lnw, s_lnb, x);
      #pragma unroll
      for (int j = 0; j < CHD; ++j) kk[j] = 0.f;
      #pragma unroll
      for (int c = 0; c < CIN; ++c) {
        #pragma unroll
        for (int j = 0; j < CHD; ++j) kk[j] += x[c] * s_wk[c * CHD + j];
      }
    }
    const float madd = 1e9f * (mask[(size_t)s * R_RES + r] - 1.0f);
    #pragma unroll
    for (int h = 0; h < NH; ++h) {
      float l = madd;
      #pragma unroll
      for (int j = 0; j < CHD; ++j) l += s_q[h * CHD + j] * kk[j];
      hmax[h] = fmaxf(hmax[h], l);
    }
  }
  #pragma unroll
  for (int h = 0; h < NH; ++h) {
    #pragma unroll
    for (int off = 32; off >= 1; off >>= 1)
      hmax[h] = fmaxf(hmax[h], __shfl_xor(hmax[h], off, 64));
  }
  if (lane == 0) {
    #pragma unroll
    for (int h = 0; h < NH; ++h) mred[wave][h] = hmax[h];
  }
  __syncthreads();
  #pragma unroll
  for (int h = 0; h < NH; ++h)
    hmax[h] = fmaxf(fmaxf(mred[0][h], mred[1][h]), fmaxf(mred[2][h], mred[3][h]));

  // ---- pass B: exp, denom, P·V ----
  float opart[HC];
  #pragma unroll
  for (int i = 0; i < HC; ++i) opart[i] = 0.f;
  float dpart[NH];
  #pragma unroll
  for (int h = 0; h < NH; ++h) dpart[h] = 0.f;

  for (int s = tid; s < S_SEQ; s += 256) {
    float kk[CHD], vv[CHD];
    if (USE_KV) {
      const float4* kp = reinterpret_cast<const float4*>(Kd + ((size_t)r * S_SEQ + s) * CHD);
      const float4* vp = reinterpret_cast<const float4*>(Vd + ((size_t)r * S_SEQ + s) * CHD);
      float4 a = kp[0], b = kp[1], c4 = vp[0], d4 = vp[1];
      kk[0] = a.x; kk[1] = a.y; kk[2] = a.z; kk[3] = a.w;
      kk[4] = b.x; kk[5] = b.y; kk[6] = b.z; kk[7] = b.w;
      vv[0] = c4.x; vv[1] = c4.y; vv[2] = c4.z; vv[3] = c4.w;
      vv[4] = d4.x; vv[5] = d4.y; vv[6] = d4.z; vv[7] = d4.w;
    } else {
      float x[CIN];
      load_ln_row(m + ((size_t)s * R_RES + r) * CIN, s_lnw, s_lnb, x);
      #pragma unroll
      for (int j = 0; j < CHD; ++j) { kk[j] = 0.f; vv[j] = 0.f; }
      #pragma unroll
      for (int c = 0; c < CIN; ++c) {
        #pragma unroll
        for (int j = 0; j < CHD; ++j) {
          kk[j] += x[c] * s_wk[c * CHD + j];
          vv[j] += x[c] * s_wv[c * CHD + j];
        }
      }
    }
    const float madd = 1e9f * (mask[(size_t)s * R_RES + r] - 1.0f);
    #pragma unroll
    for (int h = 0; h < NH; ++h) {
      float l = madd;
      #pragma unroll
      for (int j = 0; j < CHD; ++j) l += s_q[h * CHD + j] * kk[j];
      const float p = __expf(l - hmax[h]);
      dpart[h] += p;
      #pragma unroll
      for (int j = 0; j < CHD; ++j) opart[h * CHD + j] += p * vv[j];
    }
  }

  // reduce denom
  #pragma unroll
  for (int h = 0; h < NH; ++h) {
    float v = dpart[h];
    #pragma unroll
    for (int off = 32; off >= 1; off >>= 1) v += __shfl_xor(v, off, 64);
    dpart[h] = v;
  }
  if (lane == 0) {
    #pragma unroll
    for (int h = 0; h < NH; ++h) dred[wave][h] = dpart[h];
  }
  // reduce opart: lane c keeps channel c
  float keep = 0.f;
  #pragma unroll
  for (int c = 0; c < HC; ++c) {
    float val = opart[c];
    #pragma unroll
    for (int off = 32; off >= 1; off >>= 1) val += __shfl_xor(val, off, 64);
    if (lane == c) keep = val;
  }
  redw[wave][lane] = keep;
  __syncthreads();
  if (tid < HC) {
    const float tot = redw[0][tid] + redw[1][tid] + redw[2][tid] + redw[3][tid];
    const int h = tid >> 3;
    const float den = dred[0][h] + dred[1][h] + dred[2][h] + dred[3][h];
    od[(size_t)r * HC + tid] = tot / den;
  }
}

// ---------------------------------------------------------------------------
// Kernel 3: gating + output projection. One thread per (s,r) row.
// grid: S*R/256 blocks of 256.
// ---------------------------------------------------------------------------
__global__ __launch_bounds__(256) void k3_out(
    const float* __restrict__ m,
    const float* __restrict__ ln_w, const float* __restrict__ ln_b,
    const float* __restrict__ wg, const float* __restrict__ bg,
    const float* __restrict__ wo, const float* __restrict__ bo,
    const float* __restrict__ od, float* __restrict__ out) {
  __shared__ float s_wg[CIN * HC];  // [c][j]
  __shared__ float s_wo[HC * CIN];  // [j][c]
  __shared__ float s_bg[HC], s_bo[CIN], s_lnw[CIN], s_lnb[CIN];
  const int tid = threadIdx.x;
  for (int i = tid; i < CIN * HC; i += 256) { s_wg[i] = wg[i]; s_wo[i] = wo[i]; }
  if (tid < HC) s_bg[tid] = bg[tid];
  if (tid < CIN) { s_bo[tid] = bo[tid]; s_lnw[tid] = ln_w[tid]; s_lnb[tid] = ln_b[tid]; }
  __syncthreads();

  const size_t i = (size_t)blockIdx.x * 256 + tid;  // i in [0, S*R)
  const int r = (int)(i % R_RES);

  float x[CIN];
  load_ln_row(m + i * CIN, s_lnw, s_lnb, x);

  const float4* op = reinterpret_cast<const float4*>(od + (size_t)r * HC);

  float acc[CIN];
  #pragma unroll
  for (int c = 0; c < CIN; ++c) acc[c] = 0.f;

  for (int jj = 0; jj < HC; jj += 8) {
    // load this chunk's o values with static lane selection (no scratch)
    const float4 oa = op[(jj >> 2) + 0];
    const float4 ob = op[(jj >> 2) + 1];
    float och[8];
    och[0] = oa.x; och[1] = oa.y; och[2] = oa.z; och[3] = oa.w;
    och[4] = ob.x; och[5] = ob.y; och[6] = ob.z; och[7] = ob.w;
    #pragma unroll
    for (int j0 = 0; j0 < 8; ++j0) {
      const int j = jj + j0;
      float z0 = 0.f, z1 = 0.f, z2 = 0.f, z3 = 0.f;
      #pragma unroll
      for (int c = 0; c < CIN; c += 4) {
        z0 += x[c + 0] * s_wg[(c + 0) * HC + j];
        z1 += x[c + 1] * s_wg[(c + 1) * HC + j];
        z2 += x[c + 2] * s_wg[(c + 2) * HC + j];
        z3 += x[c + 3] * s_wg[(c + 3) * HC + j];
      }
      const float z = (z0 + z1) + (z2 + z3) + s_bg[j];
      const float gz = 1.0f / (1.0f + __expf(-z));
      const float t = gz * och[j0];
      #pragma unroll
      for (int c = 0; c < CIN; ++c) acc[c] += t * s_wo[j * CIN + c];
    }
  }

  float* orow = out + i * CIN;
  #pragma unroll
  for (int c = 0; c < CIN; c += 4) {
    *reinterpret_cast<float4*>(orow + c) =
        make_float4(acc[c] + s_bo[c], acc[c + 1] + s_bo[c + 1],
                    acc[c + 2] + s_bo[c + 2], acc[c + 3] + s_bo[c + 3]);
  }
}

// ---------------------------------------------------------------------------
extern "C" void kernel_launch(void* const* d_in, const int* in_sizes, int n_in,
                              void* d_out, int out_size, void* d_ws, size_t ws_size,
                              hipStream_t stream) {
  const float* m    = (const float*)d_in[0];
  const float* mask = (const float*)d_in[1];
  const float* ln_w = (const float*)d_in[2];
  const float* ln_b = (const float*)d_in[3];
  const float* wq   = (const float*)d_in[4];
  const float* wk   = (const float*)d_in[5];
  const float* wv   = (const float*)d_in[6];
  const float* wg   = (const float*)d_in[7];
  const float* bg   = (const float*)d_in[8];
  const float* wo   = (const float*)d_in[9];
  const float* bo   = (const float*)d_in[10];
  float* out = (float*)d_out;

  const size_t sizeK  = (size_t)R_RES * S_SEQ * CHD * sizeof(float);  // 25.2 MB
  const size_t sizeQP = (size_t)(S_SEQ / 256) * R_RES * CIN * sizeof(float);
  const size_t sizeO  = (size_t)R_RES * HC * sizeof(float);

  char* ws = (char*)d_ws;
  const bool use_kv = ws_size >= (2 * sizeK + sizeQP + sizeO);

  float *Kd, *Vd, *qpool_part, *od;
  if (use_kv) {
    Kd = (float*)(ws);
    Vd = (float*)(ws + sizeK);
    qpool_part = (float*)(ws + 2 * sizeK);
    od = (float*)(ws + 2 * sizeK + sizeQP);
  } else {
    Kd = nullptr;
    Vd = nullptr;
    qpool_part = (float*)(ws);
    od = (float*)(ws + sizeQP);
  }

  dim3 g1(R_RES, S_SEQ / 256);
  if (use_kv) {
    k1_ln_kv_pool<true><<<g1, 256, 0, stream>>>(m, mask, ln_w, ln_b, wk, wv, Kd, Vd, qpool_part);
    k2_attn<true><<<R_RES, 256, 0, stream>>>(m, mask, ln_w, ln_b, wq, wk, wv, qpool_part, Kd, Vd, od);
  } else {
    k1_ln_kv_pool<false><<<g1, 256, 0, stream>>>(m, mask, ln_w, ln_b, wk, wv, Kd, Vd, qpool_part);
    k2_attn<false><<<R_RES, 256, 0, stream>>>(m, mask, ln_w, ln_b, wq, wk, wv, qpool_part, Kd, Vd, od);
  }
  k3_out<<<(S_SEQ * R_RES) / 256, 256, 0, stream>>>(m, ln_w, ln_b, wg, bg, wo, bo, od, out);
}

// Round 2
// 268.637 us; speedup vs baseline: 2.6729x; 2.6729x over previous
//
#include <hip/hip_runtime.h>
#include <hip/hip_bf16.h>

#define S_SEQ 2048
#define R_RES 384
#define CIN   64
#define HC    64
#define NH    8
#define CHD   8

using bf16x8 = __attribute__((ext_vector_type(8))) short;
using f32x4  = __attribute__((ext_vector_type(4))) float;

__device__ __forceinline__ short f2bf(float v) {
  __hip_bfloat16 h = __float2bfloat16(v);
  union { __hip_bfloat16 b; short s; } u; u.b = h; return u.s;
}
__device__ __forceinline__ float bf2f(short s) {
  union { short s; __hip_bfloat16 b; } u; u.s = s; return __bfloat162float(u.b);
}

// ---------------------------------------------------------------------------
// Helpers
// ---------------------------------------------------------------------------
__device__ __forceinline__ void load_ln_row(const float* __restrict__ row,
                                            const float* __restrict__ lnw,
                                            const float* __restrict__ lnb,
                                            float* x) {
  #pragma unroll
  for (int c4 = 0; c4 < CIN / 4; ++c4) {
    float4 v = reinterpret_cast<const float4*>(row)[c4];
    x[c4 * 4 + 0] = v.x; x[c4 * 4 + 1] = v.y;
    x[c4 * 4 + 2] = v.z; x[c4 * 4 + 3] = v.w;
  }
  float mean = 0.f;
  #pragma unroll
  for (int c = 0; c < CIN; ++c) mean += x[c];
  mean *= (1.0f / CIN);
  float var = 0.f;
  #pragma unroll
  for (int c = 0; c < CIN; ++c) { float d = x[c] - mean; var += d * d; }
  var *= (1.0f / CIN);
  const float rstd = rsqrtf(var + 1e-5f);
  #pragma unroll
  for (int c = 0; c < CIN; ++c) x[c] = (x[c] - mean) * rstd * lnw[c] + lnb[c];
}

// ---------------------------------------------------------------------------
// Kernel 0: transpose + hi/lo bf16 split of wg, wo.
// wgT[j][c] = wg[c][j]; woT[cout][j] = wo[j][cout]. 4096 entries each.
// ---------------------------------------------------------------------------
__global__ __launch_bounds__(256) void k0_prep(
    const float* __restrict__ wg, const float* __restrict__ wo,
    short* __restrict__ wgT_hi, short* __restrict__ wgT_lo,
    short* __restrict__ woT_hi, short* __restrict__ woT_lo) {
  const int idx = blockIdx.x * 256 + threadIdx.x;
  if (idx >= HC * CIN) return;
  const int a = idx >> 6;   // out row
  const int b = idx & 63;   // out col
  // both tables are 64x64 with the same transpose pattern
  const float g = wg[b * HC + a];
  short gh = f2bf(g);
  wgT_hi[idx] = gh; wgT_lo[idx] = f2bf(g - bf2f(gh));
  const float o = wo[b * CIN + a];
  short oh = f2bf(o);
  woT_hi[idx] = oh; woT_lo[idx] = f2bf(o - bf2f(oh));
}

// ---------------------------------------------------------------------------
// Kernel 1: LayerNorm + K/V projection store + masked pooled sums
// ---------------------------------------------------------------------------
template <bool STORE_KV>
__global__ __launch_bounds__(256) void k1_ln_kv_pool(
    const float* __restrict__ m, const float* __restrict__ mask,
    const float* __restrict__ ln_w, const float* __restrict__ ln_b,
    const float* __restrict__ wk, const float* __restrict__ wv,
    float* __restrict__ Kd, float* __restrict__ Vd,
    float* __restrict__ qpool_part) {
  const int r = blockIdx.x;
  const int chunk = blockIdx.y;
  const int tid = threadIdx.x;
  const int lane = tid & 63;
  const int wave = tid >> 6;
  const int s = chunk * 256 + tid;

  __shared__ float s_wk[CIN * CHD];
  __shared__ float s_wv[CIN * CHD];
  __shared__ float s_lnw[CIN], s_lnb[CIN];
  __shared__ float red[4][CIN];

  if (STORE_KV) {
    for (int i = tid; i < CIN * CHD; i += 256) { s_wk[i] = wk[i]; s_wv[i] = wv[i]; }
  }
  if (tid < CIN) { s_lnw[tid] = ln_w[tid]; s_lnb[tid] = ln_b[tid]; }
  __syncthreads();

  float x[CIN];
  load_ln_row(m + ((size_t)s * R_RES + r) * CIN, s_lnw, s_lnb, x);

  if (STORE_KV) {
    float kk[CHD], vv[CHD];
    #pragma unroll
    for (int j = 0; j < CHD; ++j) { kk[j] = 0.f; vv[j] = 0.f; }
    #pragma unroll
    for (int c = 0; c < CIN; ++c) {
      const float xc = x[c];
      #pragma unroll
      for (int j = 0; j < CHD; ++j) {
        kk[j] += xc * s_wk[c * CHD + j];
        vv[j] += xc * s_wv[c * CHD + j];
      }
    }
    float* kp = Kd + ((size_t)r * S_SEQ + s) * CHD;
    float* vp = Vd + ((size_t)r * S_SEQ + s) * CHD;
    *reinterpret_cast<float4*>(kp + 0) = make_float4(kk[0], kk[1], kk[2], kk[3]);
    *reinterpret_cast<float4*>(kp + 4) = make_float4(kk[4], kk[5], kk[6], kk[7]);
    *reinterpret_cast<float4*>(vp + 0) = make_float4(vv[0], vv[1], vv[2], vv[3]);
    *reinterpret_cast<float4*>(vp + 4) = make_float4(vv[4], vv[5], vv[6], vv[7]);
  }

  const float mk = mask[(size_t)s * R_RES + r];
  float keep = 0.f;
  #pragma unroll
  for (int c = 0; c < CIN; ++c) {
    float val = x[c] * mk;
    #pragma unroll
    for (int off = 32; off >= 1; off >>= 1) val += __shfl_xor(val, off, 64);
    if (lane == c) keep = val;
  }
  red[wave][lane] = keep;
  __syncthreads();
  if (tid < CIN) {
    float tot = red[0][tid] + red[1][tid] + red[2][tid] + red[3][tid];
    qpool_part[((size_t)chunk * R_RES + r) * CIN + tid] = tot;
  }
}

// ---------------------------------------------------------------------------
// Kernel 2: per-residue global attention. grid: R_RES blocks of 256.
// ---------------------------------------------------------------------------
template <bool USE_KV>
__global__ __launch_bounds__(256) void k2_attn(
    const float* __restrict__ m, const float* __restrict__ mask,
    const float* __restrict__ ln_w, const float* __restrict__ ln_b,
    const float* __restrict__ wq, const float* __restrict__ wk,
    const float* __restrict__ wv, const float* __restrict__ qpool_part,
    const float* __restrict__ Kd, const float* __restrict__ Vd,
    float* __restrict__ od) {
  const int r = blockIdx.x;
  const int tid = threadIdx.x;
  const int lane = tid & 63;
  const int wave = tid >> 6;

  __shared__ float s_q[HC];
  __shared__ float s_qp[CIN];
  __shared__ float s_wk[CIN * CHD], s_wv[CIN * CHD];
  __shared__ float s_lnw[CIN], s_lnb[CIN];
  __shared__ float redw[4][CIN];
  __shared__ float dred[4][NH];
  __shared__ float mred[4][NH];

  if (!USE_KV) {
    for (int i = tid; i < CIN * CHD; i += 256) { s_wk[i] = wk[i]; s_wv[i] = wv[i]; }
    if (tid < CIN) { s_lnw[tid] = ln_w[tid]; s_lnb[tid] = ln_b[tid]; }
  }

  float msum = 0.f;
  for (int s = tid; s < S_SEQ; s += 256) msum += mask[(size_t)s * R_RES + r];
  #pragma unroll
  for (int off = 32; off >= 1; off >>= 1) msum += __shfl_xor(msum, off, 64);
  if (lane == 0) redw[wave][0] = msum;
  __syncthreads();
  const float msum_tot = redw[0][0] + redw[1][0] + redw[2][0] + redw[3][0];
  __syncthreads();

  if (tid < CIN) {
    float qp = 0.f;
    #pragma unroll
    for (int ch = 0; ch < S_SEQ / 256; ++ch)
      qp += qpool_part[((size_t)ch * R_RES + r) * CIN + tid];
    s_qp[tid] = qp / (msum_tot + 1e-10f);
  }
  __syncthreads();
  if (tid < HC) {
    float qj = 0.f;
    for (int c = 0; c < CIN; ++c) qj += s_qp[c] * wq[c * HC + tid];
    s_q[tid] = qj * 0.35355339059327373f;  // 1/sqrt(8)
  }
  __syncthreads();

  float hmax[NH];
  #pragma unroll
  for (int h = 0; h < NH; ++h) hmax[h] = -1e30f;

  for (int s = tid; s < S_SEQ; s += 256) {
    float kk[CHD];
    if (USE_KV) {
      const float4* kp = reinterpret_cast<const float4*>(Kd + ((size_t)r * S_SEQ + s) * CHD);
      float4 a = kp[0], b = kp[1];
      kk[0] = a.x; kk[1] = a.y; kk[2] = a.z; kk[3] = a.w;
      kk[4] = b.x; kk[5] = b.y; kk[6] = b.z; kk[7] = b.w;
    } else {
      float x[CIN];
      load_ln_row(m + ((size_t)s * R_RES + r) * CIN, s_lnw, s_lnb, x);
      #pragma unroll
      for (int j = 0; j < CHD; ++j) kk[j] = 0.f;
      #pragma unroll
      for (int c = 0; c < CIN; ++c) {
        #pragma unroll
        for (int j = 0; j < CHD; ++j) kk[j] += x[c] * s_wk[c * CHD + j];
      }
    }
    const float madd = 1e9f * (mask[(size_t)s * R_RES + r] - 1.0f);
    #pragma unroll
    for (int h = 0; h < NH; ++h) {
      float l = madd;
      #pragma unroll
      for (int j = 0; j < CHD; ++j) l += s_q[h * CHD + j] * kk[j];
      hmax[h] = fmaxf(hmax[h], l);
    }
  }
  #pragma unroll
  for (int h = 0; h < NH; ++h) {
    #pragma unroll
    for (int off = 32; off >= 1; off >>= 1)
      hmax[h] = fmaxf(hmax[h], __shfl_xor(hmax[h], off, 64));
  }
  if (lane == 0) {
    #pragma unroll
    for (int h = 0; h < NH; ++h) mred[wave][h] = hmax[h];
  }
  __syncthreads();
  #pragma unroll
  for (int h = 0; h < NH; ++h)
    hmax[h] = fmaxf(fmaxf(mred[0][h], mred[1][h]), fmaxf(mred[2][h], mred[3][h]));

  float opart[HC];
  #pragma unroll
  for (int i = 0; i < HC; ++i) opart[i] = 0.f;
  float dpart[NH];
  #pragma unroll
  for (int h = 0; h < NH; ++h) dpart[h] = 0.f;

  for (int s = tid; s < S_SEQ; s += 256) {
    float kk[CHD], vv[CHD];
    if (USE_KV) {
      const float4* kp = reinterpret_cast<const float4*>(Kd + ((size_t)r * S_SEQ + s) * CHD);
      const float4* vp = reinterpret_cast<const float4*>(Vd + ((size_t)r * S_SEQ + s) * CHD);
      float4 a = kp[0], b = kp[1], c4 = vp[0], d4 = vp[1];
      kk[0] = a.x; kk[1] = a.y; kk[2] = a.z; kk[3] = a.w;
      kk[4] = b.x; kk[5] = b.y; kk[6] = b.z; kk[7] = b.w;
      vv[0] = c4.x; vv[1] = c4.y; vv[2] = c4.z; vv[3] = c4.w;
      vv[4] = d4.x; vv[5] = d4.y; vv[6] = d4.z; vv[7] = d4.w;
    } else {
      float x[CIN];
      load_ln_row(m + ((size_t)s * R_RES + r) * CIN, s_lnw, s_lnb, x);
      #pragma unroll
      for (int j = 0; j < CHD; ++j) { kk[j] = 0.f; vv[j] = 0.f; }
      #pragma unroll
      for (int c = 0; c < CIN; ++c) {
        #pragma unroll
        for (int j = 0; j < CHD; ++j) {
          kk[j] += x[c] * s_wk[c * CHD + j];
          vv[j] += x[c] * s_wv[c * CHD + j];
        }
      }
    }
    const float madd = 1e9f * (mask[(size_t)s * R_RES + r] - 1.0f);
    #pragma unroll
    for (int h = 0; h < NH; ++h) {
      float l = madd;
      #pragma unroll
      for (int j = 0; j < CHD; ++j) l += s_q[h * CHD + j] * kk[j];
      const float p = __expf(l - hmax[h]);
      dpart[h] += p;
      #pragma unroll
      for (int j = 0; j < CHD; ++j) opart[h * CHD + j] += p * vv[j];
    }
  }

  #pragma unroll
  for (int h = 0; h < NH; ++h) {
    float v = dpart[h];
    #pragma unroll
    for (int off = 32; off >= 1; off >>= 1) v += __shfl_xor(v, off, 64);
    dpart[h] = v;
  }
  if (lane == 0) {
    #pragma unroll
    for (int h = 0; h < NH; ++h) dred[wave][h] = dpart[h];
  }
  float keep = 0.f;
  #pragma unroll
  for (int c = 0; c < HC; ++c) {
    float val = opart[c];
    #pragma unroll
    for (int off = 32; off >= 1; off >>= 1) val += __shfl_xor(val, off, 64);
    if (lane == c) keep = val;
  }
  redw[wave][lane] = keep;
  __syncthreads();
  if (tid < HC) {
    const float tot = redw[0][tid] + redw[1][tid] + redw[2][tid] + redw[3][tid];
    const int h = tid >> 3;
    const float den = dred[0][h] + dred[1][h] + dred[2][h] + dred[3][h];
    od[(size_t)r * HC + tid] = tot / den;
  }
}

// ---------------------------------------------------------------------------
// Kernel 3 (MFMA): out = (sigmoid(LN(m)@wg + bg) * o) @ wo + bo
// Split-bf16 (hi/lo), 3 MFMAs per fp32 product, mfma_f32_16x16x32_bf16.
// Block = 128 threads (2 waves); wave owns 64 consecutive rows (4 m-tiles).
// A-frag layout: lane l -> row = l&15, k = (l>>4)*8 + e (e=0..7)
// C/D layout:    lane l -> col = l&15, row = (l>>4)*4 + i
// ---------------------------------------------------------------------------
__global__ __launch_bounds__(128) void k3_mfma(
    const float* __restrict__ m,
    const float* __restrict__ ln_w, const float* __restrict__ ln_b,
    const short* __restrict__ wgT_hi, const short* __restrict__ wgT_lo,
    const short* __restrict__ woT_hi, const short* __restrict__ woT_lo,
    const float* __restrict__ bg, const float* __restrict__ bo,
    const float* __restrict__ od, float* __restrict__ out) {
  const int tid = threadIdx.x;
  const int wave = tid >> 6;
  const int lane = tid & 63;
  const int lrow = lane & 15;   // A/B frag row/col index
  const int lpart = lane >> 4;  // 0..3, k-chunk owner
  const size_t base = (size_t)blockIdx.x * 128 + (size_t)wave * 64;
  const int base_r = (int)(base % R_RES);

  __shared__ float t_lds[2][64 * 64];  // per-wave t tile, XOR-swizzled rows
  float* tw = t_lds[wave];

  // per-lane bias values for columns j = n*16 + lrow
  float bgv[4], bov[4];
  #pragma unroll
  for (int n = 0; n < 4; ++n) { bgv[n] = bg[n * 16 + lrow]; bov[n] = bo[n * 16 + lrow]; }

  // LN params for this lane's two k-chunks: c = lpart*8+e and 32+lpart*8+e
  float lw0[8], lb0[8], lw1[8], lb1[8];
  {
    const float4* w0 = reinterpret_cast<const float4*>(ln_w + lpart * 8);
    const float4* w1 = reinterpret_cast<const float4*>(ln_w + 32 + lpart * 8);
    const float4* b0 = reinterpret_cast<const float4*>(ln_b + lpart * 8);
    const float4* b1 = reinterpret_cast<const float4*>(ln_b + 32 + lpart * 8);
    float4 a = w0[0], b = w0[1], c = w1[0], d = w1[1];
    lw0[0]=a.x; lw0[1]=a.y; lw0[2]=a.z; lw0[3]=a.w; lw0[4]=b.x; lw0[5]=b.y; lw0[6]=b.z; lw0[7]=b.w;
    lw1[0]=c.x; lw1[1]=c.y; lw1[2]=c.z; lw1[3]=c.w; lw1[4]=d.x; lw1[5]=d.y; lw1[6]=d.z; lw1[7]=d.w;
    a = b0[0]; b = b0[1]; c = b1[0]; d = b1[1];
    lb0[0]=a.x; lb0[1]=a.y; lb0[2]=a.z; lb0[3]=a.w; lb0[4]=b.x; lb0[5]=b.y; lb0[6]=b.z; lb0[7]=b.w;
    lb1[0]=c.x; lb1[1]=c.y; lb1[2]=c.z; lb1[3]=c.w; lb1[4]=d.x; lb1[5]=d.y; lb1[6]=d.z; lb1[7]=d.w;
  }

  // ---- B1 frags (wgT hi/lo): [n][k], lane reads wgT[n*16+lrow][k*32 + lpart*8 ..+7]
  bf16x8 b1h[4][2], b1l[4][2];
  #pragma unroll
  for (int n = 0; n < 4; ++n) {
    #pragma unroll
    for (int k = 0; k < 2; ++k) {
      const int idx = (n * 16 + lrow) * 64 + k * 32 + lpart * 8;
      b1h[n][k] = *reinterpret_cast<const bf16x8*>(wgT_hi + idx);
      b1l[n][k] = *reinterpret_cast<const bf16x8*>(wgT_lo + idx);
    }
  }

  // ---- Pass 1: LN -> GEMM1 -> sigmoid*o -> t to LDS ----
  #pragma unroll
  for (int mt = 0; mt < 4; ++mt) {
    const size_t grow = base + mt * 16 + lrow;
    const float* mrow = m + grow * CIN;
    float x0[8], x1[8];
    {
      const float4* p0 = reinterpret_cast<const float4*>(mrow + lpart * 8);
      const float4* p1 = reinterpret_cast<const float4*>(mrow + 32 + lpart * 8);
      float4 a = p0[0], b = p0[1], c = p1[0], d = p1[1];
      x0[0]=a.x; x0[1]=a.y; x0[2]=a.z; x0[3]=a.w; x0[4]=b.x; x0[5]=b.y; x0[6]=b.z; x0[7]=b.w;
      x1[0]=c.x; x1[1]=c.y; x1[2]=c.z; x1[3]=c.w; x1[4]=d.x; x1[5]=d.y; x1[6]=d.z; x1[7]=d.w;
    }
    float s = 0.f;
    #pragma unroll
    for (int e = 0; e < 8; ++e) s += x0[e] + x1[e];
    s += __shfl_xor(s, 16, 64);
    s += __shfl_xor(s, 32, 64);
    const float mean = s * (1.0f / CIN);
    float vs = 0.f;
    #pragma unroll
    for (int e = 0; e < 8; ++e) {
      float d0 = x0[e] - mean, d1 = x1[e] - mean;
      vs += d0 * d0 + d1 * d1;
    }
    vs += __shfl_xor(vs, 16, 64);
    vs += __shfl_xor(vs, 32, 64);
    const float rstd = rsqrtf(vs * (1.0f / CIN) + 1e-5f);

    bf16x8 ah0, al0, ah1, al1;
    #pragma unroll
    for (int e = 0; e < 8; ++e) {
      float xn = (x0[e] - mean) * rstd * lw0[e] + lb0[e];
      short h = f2bf(xn);
      ah0[e] = h; al0[e] = f2bf(xn - bf2f(h));
      xn = (x1[e] - mean) * rstd * lw1[e] + lb1[e];
      h = f2bf(xn);
      ah1[e] = h; al1[e] = f2bf(xn - bf2f(h));
    }

    #pragma unroll
    for (int n = 0; n < 4; ++n) {
      f32x4 acc = {0.f, 0.f, 0.f, 0.f};
      acc = __builtin_amdgcn_mfma_f32_16x16x32_bf16(ah0, b1h[n][0], acc, 0, 0, 0);
      acc = __builtin_amdgcn_mfma_f32_16x16x32_bf16(ah1, b1h[n][1], acc, 0, 0, 0);
      acc = __builtin_amdgcn_mfma_f32_16x16x32_bf16(ah0, b1l[n][0], acc, 0, 0, 0);
      acc = __builtin_amdgcn_mfma_f32_16x16x32_bf16(ah1, b1l[n][1], acc, 0, 0, 0);
      acc = __builtin_amdgcn_mfma_f32_16x16x32_bf16(al0, b1h[n][0], acc, 0, 0, 0);
      acc = __builtin_amdgcn_mfma_f32_16x16x32_bf16(al1, b1h[n][1], acc, 0, 0, 0);
      const int j = n * 16 + lrow;
      #pragma unroll
      for (int i = 0; i < 4; ++i) {
        const int rl = mt * 16 + lpart * 4 + i;
        int r = base_r + rl; if (r >= R_RES) r -= R_RES;
        const float z = acc[i] + bgv[n];
        const float g = 1.0f / (1.0f + __expf(-z));
        const float t = g * od[(size_t)r * HC + j];
        const int off = ((rl * 256 + j * 4)) ^ ((rl & 7) << 4);
        *reinterpret_cast<float*>(reinterpret_cast<char*>(tw) + off) = t;
      }
    }
  }

  __syncthreads();  // safe ordering of LDS writes -> reads (also within wave)

  // ---- B2 frags (woT hi/lo) replace B1 ----
  bf16x8 b2h[4][2], b2l[4][2];
  #pragma unroll
  for (int n = 0; n < 4; ++n) {
    #pragma unroll
    for (int k = 0; k < 2; ++k) {
      const int idx = (n * 16 + lrow) * 64 + k * 32 + lpart * 8;
      b2h[n][k] = *reinterpret_cast<const bf16x8*>(woT_hi + idx);
      b2l[n][k] = *reinterpret_cast<const bf16x8*>(woT_lo + idx);
    }
  }

  // ---- Pass 2: t -> GEMM2 -> out ----
  #pragma unroll
  for (int mt = 0; mt < 4; ++mt) {
    const int rl2 = mt * 16 + lrow;
    const int swz = (rl2 & 7) << 4;
    bf16x8 ah0, al0, ah1, al1;
    {
      const int a0 = rl2 * 256 + lpart * 32;         // k-chunk 0: j = lpart*8..
      const int a1 = rl2 * 256 + 128 + lpart * 32;   // k-chunk 1: j = 32+lpart*8..
      char* tb = reinterpret_cast<char*>(tw);
      float4 u0 = *reinterpret_cast<float4*>(tb + (a0 ^ swz));
      float4 u1 = *reinterpret_cast<float4*>(tb + ((a0 + 16) ^ swz));
      float4 u2 = *reinterpret_cast<float4*>(tb + (a1 ^ swz));
      float4 u3 = *reinterpret_cast<float4*>(tb + ((a1 + 16) ^ swz));
      float t0[8] = {u0.x, u0.y, u0.z, u0.w, u1.x, u1.y, u1.z, u1.w};
      float t1[8] = {u2.x, u2.y, u2.z, u2.w, u3.x, u3.y, u3.z, u3.w};
      #pragma unroll
      for (int e = 0; e < 8; ++e) {
        short h = f2bf(t0[e]);
        ah0[e] = h; al0[e] = f2bf(t0[e] - bf2f(h));
        h = f2bf(t1[e]);
        ah1[e] = h; al1[e] = f2bf(t1[e] - bf2f(h));
      }
    }
    #pragma unroll
    for (int n = 0; n < 4; ++n) {
      f32x4 acc = {0.f, 0.f, 0.f, 0.f};
      acc = __builtin_amdgcn_mfma_f32_16x16x32_bf16(ah0, b2h[n][0], acc, 0, 0, 0);
      acc = __builtin_amdgcn_mfma_f32_16x16x32_bf16(ah1, b2h[n][1], acc, 0, 0, 0);
      acc = __builtin_amdgcn_mfma_f32_16x16x32_bf16(ah0, b2l[n][0], acc, 0, 0, 0);
      acc = __builtin_amdgcn_mfma_f32_16x16x32_bf16(ah1, b2l[n][1], acc, 0, 0, 0);
      acc = __builtin_amdgcn_mfma_f32_16x16x32_bf16(al0, b2h[n][0], acc, 0, 0, 0);
      acc = __builtin_amdgcn_mfma_f32_16x16x32_bf16(al1, b2h[n][1], acc, 0, 0, 0);
      const int cc = n * 16 + lrow;
      #pragma unroll
      for (int i = 0; i < 4; ++i) {
        const size_t grow = base + mt * 16 + lpart * 4 + i;
        out[grow * CIN + cc] = acc[i] + bov[n];
      }
    }
  }
}

// ---------------------------------------------------------------------------
extern "C" void kernel_launch(void* const* d_in, const int* in_sizes, int n_in,
                              void* d_out, int out_size, void* d_ws, size_t ws_size,
                              hipStream_t stream) {
  const float* m    = (const float*)d_in[0];
  const float* mask = (const float*)d_in[1];
  const float* ln_w = (const float*)d_in[2];
  const float* ln_b = (const float*)d_in[3];
  const float* wq   = (const float*)d_in[4];
  const float* wk   = (const float*)d_in[5];
  const float* wv   = (const float*)d_in[6];
  const float* wg   = (const float*)d_in[7];
  const float* bg   = (const float*)d_in[8];
  const float* wo   = (const float*)d_in[9];
  const float* bo   = (const float*)d_in[10];
  float* out = (float*)d_out;

  const size_t sizeK  = (size_t)R_RES * S_SEQ * CHD * sizeof(float);  // 25.2 MB
  const size_t sizeQP = (size_t)(S_SEQ / 256) * R_RES * CIN * sizeof(float);
  const size_t sizeO  = (size_t)R_RES * HC * sizeof(float);
  const size_t sizeW  = (size_t)HC * CIN * sizeof(short);  // 8 KB per table

  char* ws = (char*)d_ws;
  const bool use_kv = ws_size >= (2 * sizeK + sizeQP + sizeO + 4 * sizeW);

  float *Kd, *Vd, *qpool_part, *od;
  char* wbase;
  if (use_kv) {
    Kd = (float*)(ws);
    Vd = (float*)(ws + sizeK);
    qpool_part = (float*)(ws + 2 * sizeK);
    od = (float*)(ws + 2 * sizeK + sizeQP);
    wbase = ws + 2 * sizeK + sizeQP + sizeO;
  } else {
    Kd = nullptr;
    Vd = nullptr;
    qpool_part = (float*)(ws);
    od = (float*)(ws + sizeQP);
    wbase = ws + sizeQP + sizeO;
  }
  short* wgT_hi = (short*)(wbase);
  short* wgT_lo = (short*)(wbase + sizeW);
  short* woT_hi = (short*)(wbase + 2 * sizeW);
  short* woT_lo = (short*)(wbase + 3 * sizeW);

  k0_prep<<<(HC * CIN + 255) / 256, 256, 0, stream>>>(wg, wo, wgT_hi, wgT_lo, woT_hi, woT_lo);

  dim3 g1(R_RES, S_SEQ / 256);
  if (use_kv) {
    k1_ln_kv_pool<true><<<g1, 256, 0, stream>>>(m, mask, ln_w, ln_b, wk, wv, Kd, Vd, qpool_part);
    k2_attn<true><<<R_RES, 256, 0, stream>>>(m, mask, ln_w, ln_b, wq, wk, wv, qpool_part, Kd, Vd, od);
  } else {
    k1_ln_kv_pool<false><<<g1, 256, 0, stream>>>(m, mask, ln_w, ln_b, wk, wv, Kd, Vd, qpool_part);
    k2_attn<false><<<R_RES, 256, 0, stream>>>(m, mask, ln_w, ln_b, wq, wk, wv, qpool_part, Kd, Vd, od);
  }
  k3_mfma<<<(S_SEQ * R_RES) / 128, 128, 0, stream>>>(
      m, ln_w, ln_b, wgT_hi, wgT_lo, woT_hi, woT_lo, bg, bo, od, out);
}